// Round 1
// baseline (4714.455 us; speedup 1.0000x reference)
//
#include <hip/hip_runtime.h>
#include <hip/hip_bf16.h>
#include <math.h>

#define BB 4
#define TT 2048
#define CC 768
#define HH 12
#define HDIM 64
#define C4 3072
#define MM (BB*TT)   // 8192 rows
#define EPSL 1e-5f

// ---------------------------------------------------------------------------
// LayerNorm: one block per row (C=768, 256 threads -> 3 elems/thread)
// ---------------------------------------------------------------------------
__global__ __launch_bounds__(256) void ln_k(const float* __restrict__ X,
                                            const float* __restrict__ G,
                                            const float* __restrict__ Be,
                                            float* __restrict__ O)
{
    int row = blockIdx.x;
    const float* xr = X + (size_t)row * CC;
    int t = threadIdx.x;
    float v0 = xr[t], v1 = xr[t + 256], v2 = xr[t + 512];
    float s  = v0 + v1 + v2;
    float sq = v0*v0 + v1*v1 + v2*v2;
    #pragma unroll
    for (int off = 32; off; off >>= 1) {
        s  += __shfl_xor(s,  off);
        sq += __shfl_xor(sq, off);
    }
    __shared__ float red[8];
    int wv = t >> 6, ln = t & 63;
    if (ln == 0) { red[wv] = s; red[4 + wv] = sq; }
    __syncthreads();
    s  = red[0] + red[1] + red[2] + red[3];
    sq = red[4] + red[5] + red[6] + red[7];
    float mu  = s * (1.0f / CC);
    float var = sq * (1.0f / CC) - mu * mu;
    float rs  = rsqrtf(var + EPSL);
    float* orow = O + (size_t)row * CC;
    orow[t]       = (v0 - mu) * rs * G[t]       + Be[t];
    orow[t + 256] = (v1 - mu) * rs * G[t + 256] + Be[t + 256];
    orow[t + 512] = (v2 - mu) * rs * G[t + 512] + Be[t + 512];
}

// ---------------------------------------------------------------------------
// fp32 tiled GEMM: C[M,N] = A[M,K] @ B[K,N] (+bias) (+residual) (ReLU)
// BLAYOUT 0: B row-major [K,N].  BLAYOUT 1: B head-major [N/64, K, 64] (wq/wk/wv).
// 64x64 tile, BK=16, 256 threads, 4x4 microtile. LDS stride 65 -> conflict-free.
// Requires M%64==0, N%64==0, K%16==0 (true for all call sites).
// ---------------------------------------------------------------------------
template<int BLAYOUT, bool RELU, bool RESID>
__global__ __launch_bounds__(256) void gemm_k(const float* __restrict__ A,
                                              const float* __restrict__ Bm,
                                              const float* __restrict__ bias,
                                              const float* __restrict__ Rs,
                                              float* __restrict__ O,
                                              int M, int N, int K)
{
    __shared__ float As[16][65];   // [k][m]
    __shared__ float Bs[16][65];   // [k][n]
    int bn = blockIdx.x, bm = blockIdx.y;
    int tid = threadIdx.x;
    int tx = tid & 15, ty = tid >> 4;
    int ac = tid & 15, ar = tid >> 4;       // A stage: k-col ac, rows ar*4+i
    int bcol = tid & 63, brow = tid >> 6;   // B stage: n-col bcol, k rows brow*4+i
    float acc[4][4] = {{0.f}};

    for (int k0 = 0; k0 < K; k0 += 16) {
        #pragma unroll
        for (int i = 0; i < 4; ++i) {
            int m = ar * 4 + i;
            As[ac][m] = A[(size_t)(bm * 64 + m) * K + k0 + ac];
        }
        #pragma unroll
        for (int i = 0; i < 4; ++i) {
            int kk = brow * 4 + i;
            float v;
            if (BLAYOUT == 0) v = Bm[(size_t)(k0 + kk) * N + bn * 64 + bcol];
            else              v = Bm[((size_t)bn * K + (k0 + kk)) * 64 + bcol];
            Bs[kk][bcol] = v;
        }
        __syncthreads();
        #pragma unroll
        for (int kk = 0; kk < 16; ++kk) {
            float a0 = As[kk][ty*4+0], a1 = As[kk][ty*4+1],
                  a2 = As[kk][ty*4+2], a3 = As[kk][ty*4+3];
            float b0 = Bs[kk][tx*4+0], b1 = Bs[kk][tx*4+1],
                  b2 = Bs[kk][tx*4+2], b3 = Bs[kk][tx*4+3];
            acc[0][0] += a0*b0; acc[0][1] += a0*b1; acc[0][2] += a0*b2; acc[0][3] += a0*b3;
            acc[1][0] += a1*b0; acc[1][1] += a1*b1; acc[1][2] += a1*b2; acc[1][3] += a1*b3;
            acc[2][0] += a2*b0; acc[2][1] += a2*b1; acc[2][2] += a2*b2; acc[2][3] += a2*b3;
            acc[3][0] += a3*b0; acc[3][1] += a3*b1; acc[3][2] += a3*b2; acc[3][3] += a3*b3;
        }
        __syncthreads();
    }

    #pragma unroll
    for (int i = 0; i < 4; ++i) {
        int m  = bm * 64 + ty * 4 + i;
        int n0 = bn * 64 + tx * 4;
        #pragma unroll
        for (int j = 0; j < 4; ++j) {
            float v = acc[i][j] + bias[n0 + j];
            if (RESID) v += Rs[(size_t)m * N + n0 + j];
            if (RELU)  v = fmaxf(v, 0.f);
            O[(size_t)m * N + n0 + j] = v;
        }
    }
}

// ---------------------------------------------------------------------------
// Causal attention, flash-style. q/k/v layout [B,T,H,HD]. One wave per query
// row; block = 4 waves = 4 consecutive t rows of one (b,h). K/V chunks of 64
// rows staged in LDS (row stride 68 floats: 16B-aligned float4, bank-optimal).
// Online softmax (m,l running), NO 1/sqrt(d) scaling (matches reference).
// ---------------------------------------------------------------------------
__global__ __launch_bounds__(256) void attn_k(const float* __restrict__ Q,
                                              const float* __restrict__ Kp,
                                              const float* __restrict__ Vp,
                                              float* __restrict__ O)
{
    __shared__ float kt[64][68];
    __shared__ float vt[64][68];
    __shared__ float ql[4][64];

    int blk = blockIdx.x;
    int t4  = blk & (TT/4 - 1);
    int bh  = blk / (TT/4);
    int b = bh / HH, h = bh % HH;
    int wv = threadIdx.x >> 6, lane = threadIdx.x & 63;
    int t = t4 * 4 + wv;

    size_t qoff = ((size_t)(b * TT + t) * HH + h) * HDIM;
    float qreg = Q[qoff + lane];
    ql[wv][lane] = qreg;

    float o = 0.f, mrun = -INFINITY, lrun = 0.f;
    int tmaxblk = t4 * 4 + 3;
    int sr  = threadIdx.x >> 2;          // staging row 0..63
    int sc0 = (threadIdx.x & 3) * 16;    // staging col start

    for (int s0 = 0; s0 <= tmaxblk; s0 += 64) {
        __syncthreads();
        {   // cooperative stage of K/V rows s0..s0+63 (always < T: T%64==0)
            int s = s0 + sr;
            const float4* kp4 = (const float4*)(Kp + ((size_t)(b * TT + s) * HH + h) * HDIM + sc0);
            const float4* vp4 = (const float4*)(Vp + ((size_t)(b * TT + s) * HH + h) * HDIM + sc0);
            float4* kd = (float4*)&kt[sr][sc0];
            float4* vd = (float4*)&vt[sr][sc0];
            #pragma unroll
            for (int i = 0; i < 4; ++i) { kd[i] = kp4[i]; vd[i] = vp4[i]; }
        }
        __syncthreads();

        if (s0 <= t) {   // wave-uniform guard: skip fully-masked chunks
            int sj = s0 + lane;
            float sc = -INFINITY;
            if (sj <= t) {
                const float4* qv = (const float4*)ql[wv];
                const float4* kv = (const float4*)&kt[lane][0];
                float acc = 0.f;
                #pragma unroll
                for (int d4 = 0; d4 < 16; ++d4) {
                    float4 a = qv[d4], kk4 = kv[d4];
                    acc += a.x*kk4.x + a.y*kk4.y + a.z*kk4.z + a.w*kk4.w;
                }
                sc = acc;
            }
            float cm = sc;
            #pragma unroll
            for (int off = 32; off; off >>= 1) cm = fmaxf(cm, __shfl_xor(cm, off));
            float mnew = fmaxf(mrun, cm);
            float p = (sj <= t) ? __expf(sc - mnew) : 0.f;
            float ps = p;
            #pragma unroll
            for (int off = 32; off; off >>= 1) ps += __shfl_xor(ps, off);
            float scale = __expf(mrun - mnew);   // first chunk: exp(-inf)=0
            lrun = lrun * scale + ps;
            o *= scale;
            if (t - s0 >= 63) {
                #pragma unroll
                for (int j = 0; j < 64; ++j)
                    o += __shfl(p, j) * vt[j][lane];
            } else {
                int jmax = t - s0;
                for (int j = 0; j <= jmax; ++j)
                    o += __shfl(p, j) * vt[j][lane];
            }
            mrun = mnew;
        }
    }
    O[qoff + lane] = o / lrun;   // lane == d
}

// ---------------------------------------------------------------------------
// Orchestration.
// ws layout (floats), S = MM*CC = 6291456:
//   [0,S)   q      [B,T,H,HD]
//   [S,2S)  k
//   [2S,3S) v
//   [3S,4S) attn   [B,T,H,HD] == [B,T,C]
//   [4S,5S) h      (LN output, reused for LN1 and LN2)
//   mid [MM,C4] = 4S floats exactly aliases [0,4S) (q/k/v/attn dead by then)
// Total: 5S*4 = 125,829,120 bytes of d_ws.
// ---------------------------------------------------------------------------
extern "C" void kernel_launch(void* const* d_in, const int* in_sizes, int n_in,
                              void* d_out, int out_size, void* d_ws, size_t ws_size,
                              hipStream_t stream)
{
    const float* x   = (const float*)d_in[0];
    const float* wq  = (const float*)d_in[1];
    const float* bq  = (const float*)d_in[2];
    const float* wk  = (const float*)d_in[3];
    const float* bk  = (const float*)d_in[4];
    const float* wvw = (const float*)d_in[5];
    const float* bv  = (const float*)d_in[6];
    const float* wp  = (const float*)d_in[7];
    const float* bp  = (const float*)d_in[8];
    const float* w1  = (const float*)d_in[9];
    const float* b1  = (const float*)d_in[10];
    const float* w2  = (const float*)d_in[11];
    const float* b2  = (const float*)d_in[12];
    const float* g1  = (const float*)d_in[13];
    const float* be1 = (const float*)d_in[14];
    const float* g2  = (const float*)d_in[15];
    const float* be2 = (const float*)d_in[16];

    float* out = (float*)d_out;
    float* wsf = (float*)d_ws;
    const size_t S = (size_t)MM * CC;
    float* q    = wsf;
    float* kbuf = wsf + S;
    float* vbuf = wsf + 2 * S;
    float* attn = wsf + 3 * S;
    float* hbuf = wsf + 4 * S;
    float* mid  = wsf;               // aliases q..attn after they are dead

    dim3 g768(CC / 64, MM / 64);
    dim3 g3072(C4 / 64, MM / 64);

    // --- attention sublayer ---
    ln_k<<<MM, 256, 0, stream>>>(x, g1, be1, hbuf);
    gemm_k<1,false,false><<<g768, 256, 0, stream>>>(hbuf, wq,  bq, nullptr, q,    MM, CC, CC);
    gemm_k<1,false,false><<<g768, 256, 0, stream>>>(hbuf, wk,  bk, nullptr, kbuf, MM, CC, CC);
    gemm_k<1,false,false><<<g768, 256, 0, stream>>>(hbuf, wvw, bv, nullptr, vbuf, MM, CC, CC);
    attn_k<<<BB * HH * (TT / 4), 256, 0, stream>>>(q, kbuf, vbuf, attn);
    gemm_k<0,false,true><<<g768, 256, 0, stream>>>(attn, wp, bp, x, out, MM, CC, CC);

    // --- MLP sublayer ---
    ln_k<<<MM, 256, 0, stream>>>(out, g2, be2, hbuf);
    gemm_k<0,true,false><<<g3072, 256, 0, stream>>>(hbuf, w1, b1, nullptr, mid, MM, C4, CC);
    gemm_k<0,false,true><<<g768, 256, 0, stream>>>(mid, w2, b2, out, out, MM, CC, C4);
}

// Round 2
// 2828.617 us; speedup vs baseline: 1.6667x; 1.6667x over previous
//
#include <hip/hip_runtime.h>
#include <hip/hip_bf16.h>
#include <math.h>

#define BB 4
#define TT 2048
#define CC 768
#define HH 12
#define HDIM 64
#define C4 3072
#define MM (BB*TT)   // 8192 rows
#define EPSL 1e-5f

typedef __bf16 bf16x8 __attribute__((ext_vector_type(8)));
typedef float f32x4 __attribute__((ext_vector_type(4)));

__device__ __forceinline__ ushort f2bf(float f) {
    union { float f; unsigned u; } v; v.f = f;
    unsigned r = v.u + 0x7fffu + ((v.u >> 16) & 1u);
    return (ushort)(r >> 16);
}

__device__ __forceinline__ void glds16(const void* g, void* l) {
    __builtin_amdgcn_global_load_lds(
        (const __attribute__((address_space(1))) void*)g,
        (__attribute__((address_space(3))) void*)l, 16, 0, 0);
}

// ---------------------------------------------------------------------------
// LayerNorm: one block per row, fp32 in -> bf16 out
// ---------------------------------------------------------------------------
__global__ __launch_bounds__(256) void ln_k(const float* __restrict__ X,
                                            const float* __restrict__ G,
                                            const float* __restrict__ Be,
                                            ushort* __restrict__ O)
{
    int row = blockIdx.x;
    const float* xr = X + (size_t)row * CC;
    int t = threadIdx.x;
    float v0 = xr[t], v1 = xr[t + 256], v2 = xr[t + 512];
    float s  = v0 + v1 + v2;
    float sq = v0*v0 + v1*v1 + v2*v2;
    #pragma unroll
    for (int off = 32; off; off >>= 1) {
        s  += __shfl_xor(s,  off);
        sq += __shfl_xor(sq, off);
    }
    __shared__ float red[8];
    int wv = t >> 6, ln = t & 63;
    if (ln == 0) { red[wv] = s; red[4 + wv] = sq; }
    __syncthreads();
    s  = red[0] + red[1] + red[2] + red[3];
    sq = red[4] + red[5] + red[6] + red[7];
    float mu  = s * (1.0f / CC);
    float var = sq * (1.0f / CC) - mu * mu;
    float rs  = rsqrtf(var + EPSL);
    ushort* orow = O + (size_t)row * CC;
    orow[t]       = f2bf((v0 - mu) * rs * G[t]       + Be[t]);
    orow[t + 256] = f2bf((v1 - mu) * rs * G[t + 256] + Be[t + 256]);
    orow[t + 512] = f2bf((v2 - mu) * rs * G[t + 512] + Be[t + 512]);
}

// ---------------------------------------------------------------------------
// Weight repack: fp32 W -> bf16 W^T [N][K] via 64x64 LDS transpose tile.
// MODE 0: W row-major [K][N].  MODE 1: W is per-head [H][768][64] (qkv),
//   logical (k,n) -> W[((n>>6)*768 + k)*64 + (n&63)].
// Grid (N/64, K/64).
// ---------------------------------------------------------------------------
template<int MODE>
__global__ __launch_bounds__(256) void repack_k(const float* __restrict__ W,
                                                ushort* __restrict__ WT,
                                                int K, int N, int outStride)
{
    __shared__ float tl[64][65];
    int n0 = blockIdx.x * 64, k0 = blockIdx.y * 64;
    int c = threadIdx.x & 63, rr = threadIdx.x >> 6;
    #pragma unroll
    for (int i = 0; i < 16; ++i) {
        int r = i * 4 + rr;
        float v;
        if (MODE == 0) v = W[(size_t)(k0 + r) * N + n0 + c];
        else           v = W[((size_t)(n0 >> 6) * CC + k0 + r) * 64 + c];
        tl[r][c] = v;
    }
    __syncthreads();
    #pragma unroll
    for (int i = 0; i < 16; ++i) {
        int r = i * 4 + rr;   // n within tile
        WT[(size_t)(n0 + r) * outStride + k0 + c] = f2bf(tl[c][r]);
    }
}

// ---------------------------------------------------------------------------
// bf16 MFMA GEMM (m97 structure): C[M,N] = A[M,K] @ BT[N,K]^T, fp32 accum.
// 128x128 tile, BK=32, 4 waves (2x2 of 64x64), 16x16x32 MFMA, 4x4 frags.
// global_load_lds width-16 staging into linear LDS.
// EPI 1: split-QKV (3 f32 outs [M][768] + per-segment bias)
// EPI 2: f32 out = acc + bias + resid
// EPI 3: bf16 out = relu(acc + bias)
// ---------------------------------------------------------------------------
template<int EPI>
__global__ __launch_bounds__(256) void gemm_bf16(
    const ushort* __restrict__ A, const ushort* __restrict__ BT,
    int M, int N, int K,
    float* __restrict__ o0, float* __restrict__ o1, float* __restrict__ o2,
    const float* __restrict__ bias0, const float* __restrict__ bias1,
    const float* __restrict__ bias2,
    const float* __restrict__ resid, ushort* __restrict__ obf)
{
    __shared__ ushort Al[128 * 32];
    __shared__ ushort Bl[128 * 32];
    int bn = blockIdx.x, bm = blockIdx.y;
    int tid = threadIdx.x;
    int lane = tid & 63;
    int w = tid >> 6;
    int wr = (w >> 1) * 64, wc = (w & 1) * 64;
    int fr = lane & 15, kh = lane >> 4;

    f32x4 acc[4][4] = {};

    const size_t aRow = (size_t)bm * 128;
    const size_t bRow = (size_t)bn * 128;

    for (int k0 = 0; k0 < K; k0 += 32) {
        #pragma unroll
        for (int r = 0; r < 2; ++r) {
            int e = r * 256 + tid;
            glds16(A  + (aRow + (e >> 2)) * K + k0 + (e & 3) * 8, Al + e * 8);
            glds16(BT + (bRow + (e >> 2)) * K + k0 + (e & 3) * 8, Bl + e * 8);
        }
        __syncthreads();   // compiler drains vmcnt before barrier
        bf16x8 av[4], bv[4];
        #pragma unroll
        for (int i = 0; i < 4; ++i)
            av[i] = *(const bf16x8*)&Al[(wr + i * 16 + fr) * 32 + kh * 8];
        #pragma unroll
        for (int i = 0; i < 4; ++i)
            bv[i] = *(const bf16x8*)&Bl[(wc + i * 16 + fr) * 32 + kh * 8];
        #pragma unroll
        for (int i = 0; i < 4; ++i)
            #pragma unroll
            for (int j = 0; j < 4; ++j)
                acc[i][j] = __builtin_amdgcn_mfma_f32_16x16x32_bf16(av[i], bv[j], acc[i][j], 0, 0, 0);
        __syncthreads();
    }

    // Epilogue. C/D layout (m89-verified): col = lane&15, row = (lane>>4)*4 + r
    if (EPI == 1) {
        int seg = (bn * 128) / CC;
        float* op = seg == 0 ? o0 : (seg == 1 ? o1 : o2);
        const float* bsp = seg == 0 ? bias0 : (seg == 1 ? bias1 : bias2);
        int cb = bn * 128 - seg * CC + wc;
        #pragma unroll
        for (int i = 0; i < 4; ++i) {
            int row0 = bm * 128 + wr + i * 16 + kh * 4;
            #pragma unroll
            for (int j = 0; j < 4; ++j) {
                int col = cb + j * 16 + fr;
                float bsv = bsp[col];
                #pragma unroll
                for (int r = 0; r < 4; ++r)
                    op[(size_t)(row0 + r) * CC + col] = acc[i][j][r] + bsv;
            }
        }
    } else if (EPI == 2) {
        int cb = bn * 128 + wc;
        #pragma unroll
        for (int i = 0; i < 4; ++i) {
            int row0 = bm * 128 + wr + i * 16 + kh * 4;
            #pragma unroll
            for (int j = 0; j < 4; ++j) {
                int col = cb + j * 16 + fr;
                float bsv = bias0[col];
                #pragma unroll
                for (int r = 0; r < 4; ++r) {
                    size_t idx = (size_t)(row0 + r) * N + col;
                    o0[idx] = acc[i][j][r] + bsv + resid[idx];
                }
            }
        }
    } else {  // EPI 3
        int cb = bn * 128 + wc;
        #pragma unroll
        for (int i = 0; i < 4; ++i) {
            int row0 = bm * 128 + wr + i * 16 + kh * 4;
            #pragma unroll
            for (int j = 0; j < 4; ++j) {
                int col = cb + j * 16 + fr;
                float bsv = bias0[col];
                #pragma unroll
                for (int r = 0; r < 4; ++r) {
                    float v = fmaxf(acc[i][j][r] + bsv, 0.f);
                    obf[(size_t)(row0 + r) * N + col] = f2bf(v);
                }
            }
        }
    }
}

// ---------------------------------------------------------------------------
// Causal attention, flash-style, fp32 q/k/v [M][768] (col = h*64+d), bf16 out.
// One wave per query row. K rows in LDS with per-row chunk rotation to kill
// the stride-68 8-way bank conflict on ds_read_b128.
// ---------------------------------------------------------------------------
__global__ __launch_bounds__(256) void attn_k(const float* __restrict__ Q,
                                              const float* __restrict__ Kp,
                                              const float* __restrict__ Vp,
                                              ushort* __restrict__ Ob)
{
    __shared__ float kt[64][68];
    __shared__ float vt[64][68];
    __shared__ float ql[4][64];

    int blk = blockIdx.x;
    int t4  = blk & (TT/4 - 1);
    int bh  = blk / (TT/4);
    int b = bh / HH, h = bh % HH;
    int wv = threadIdx.x >> 6, lane = threadIdx.x & 63;
    int t = t4 * 4 + wv;

    size_t qoff = ((size_t)(b * TT + t) * HH + h) * HDIM;
    ql[wv][lane] = Q[qoff + lane];

    float o = 0.f, mrun = -INFINITY, lrun = 0.f;
    int tmaxblk = t4 * 4 + 3;
    int sr  = threadIdx.x >> 2;          // staging row 0..63
    int cb4 = (threadIdx.x & 3) * 4;     // first float4-chunk index

    for (int s0 = 0; s0 <= tmaxblk; s0 += 64) {
        __syncthreads();
        {
            int s = s0 + sr;
            const float4* kp4 = (const float4*)(Kp + ((size_t)(b * TT + s) * HH + h) * HDIM + cb4 * 4);
            const float4* vp4 = (const float4*)(Vp + ((size_t)(b * TT + s) * HH + h) * HDIM + cb4 * 4);
            float4* vd = (float4*)&vt[sr][cb4 * 4];
            #pragma unroll
            for (int i = 0; i < 4; ++i) {
                int p = (cb4 + i + sr) & 15;      // rotated K chunk
                *(float4*)&kt[sr][p * 4] = kp4[i];
                vd[i] = vp4[i];
            }
        }
        __syncthreads();

        if (s0 <= t) {
            int sj = s0 + lane;
            float sc = -INFINITY;
            if (sj <= t) {
                const float4* qv = (const float4*)ql[wv];
                float acc = 0.f;
                #pragma unroll
                for (int d4 = 0; d4 < 16; ++d4) {
                    float4 a = qv[d4];
                    int p = (d4 + lane) & 15;
                    float4 kk4 = *(const float4*)&kt[lane][p * 4];
                    acc += a.x*kk4.x + a.y*kk4.y + a.z*kk4.z + a.w*kk4.w;
                }
                sc = acc;
            }
            float cm = sc;
            #pragma unroll
            for (int off = 32; off; off >>= 1) cm = fmaxf(cm, __shfl_xor(cm, off));
            float mnew = fmaxf(mrun, cm);
            float p = (sj <= t) ? __expf(sc - mnew) : 0.f;
            float ps = p;
            #pragma unroll
            for (int off = 32; off; off >>= 1) ps += __shfl_xor(ps, off);
            float scale = __expf(mrun - mnew);
            lrun = lrun * scale + ps;
            o *= scale;
            if (t - s0 >= 63) {
                #pragma unroll
                for (int j = 0; j < 64; ++j)
                    o += __shfl(p, j) * vt[j][lane];
            } else {
                int jmax = t - s0;
                for (int j = 0; j <= jmax; ++j)
                    o += __shfl(p, j) * vt[j][lane];
            }
            mrun = mnew;
        }
    }
    Ob[qoff + lane] = f2bf(o / lrun);
}

// ---------------------------------------------------------------------------
// Orchestration. ws layout (bytes):
//   WTqkv bf16 [2304][768]   3.54 MB
//   WTp   bf16 [768][768]    1.18 MB
//   WT1   bf16 [3072][768]   4.72 MB
//   WT2   bf16 [768][3072]   4.72 MB
//   hbf   bf16 [8192][768]  12.58 MB   (LN1 and LN2 output)
//   attnb bf16 [8192][768]  12.58 MB
//   qb,kb,vb f32 [8192][768] 25.17 MB each
//   midb  bf16 [8192][3072] aliases qb+kb exactly (dead after attn)
// Total ~114.8 MB.
// ---------------------------------------------------------------------------
extern "C" void kernel_launch(void* const* d_in, const int* in_sizes, int n_in,
                              void* d_out, int out_size, void* d_ws, size_t ws_size,
                              hipStream_t stream)
{
    const float* x   = (const float*)d_in[0];
    const float* wq  = (const float*)d_in[1];
    const float* bq  = (const float*)d_in[2];
    const float* wk  = (const float*)d_in[3];
    const float* bk  = (const float*)d_in[4];
    const float* wvw = (const float*)d_in[5];
    const float* bv  = (const float*)d_in[6];
    const float* wp  = (const float*)d_in[7];
    const float* bp  = (const float*)d_in[8];
    const float* w1  = (const float*)d_in[9];
    const float* b1  = (const float*)d_in[10];
    const float* w2  = (const float*)d_in[11];
    const float* b2  = (const float*)d_in[12];
    const float* g1  = (const float*)d_in[13];
    const float* be1 = (const float*)d_in[14];
    const float* g2  = (const float*)d_in[15];
    const float* be2 = (const float*)d_in[16];

    float* out = (float*)d_out;
    const size_t S = (size_t)MM * CC;

    ushort* WTqkv = (ushort*)d_ws;
    ushort* WTp   = WTqkv + (size_t)2304 * 768;
    ushort* WT1   = WTp   + (size_t)768 * 768;
    ushort* WT2   = WT1   + (size_t)3072 * 768;
    ushort* hbf   = WT2   + (size_t)768 * 3072;
    ushort* attnb = hbf   + S;
    float*  qb    = (float*)(attnb + S);
    float*  kb    = qb + S;
    float*  vb    = kb + S;
    ushort* midb  = (ushort*)qb;   // [8192][3072] bf16 == qb+kb bytes exactly

    dim3 rg(12, 12);
    repack_k<1><<<rg, 256, 0, stream>>>(wq,  WTqkv,                      768, 768, 768);
    repack_k<1><<<rg, 256, 0, stream>>>(wk,  WTqkv + (size_t)768*768,    768, 768, 768);
    repack_k<1><<<rg, 256, 0, stream>>>(wvw, WTqkv + (size_t)2*768*768,  768, 768, 768);
    repack_k<0><<<rg, 256, 0, stream>>>(wp,  WTp, 768, 768, 768);
    repack_k<0><<<dim3(48, 12), 256, 0, stream>>>(w1, WT1, 768, 3072, 768);
    repack_k<0><<<dim3(12, 48), 256, 0, stream>>>(w2, WT2, 3072, 768, 3072);

    // --- attention sublayer ---
    ln_k<<<MM, 256, 0, stream>>>(x, g1, be1, hbf);
    gemm_bf16<1><<<dim3(18, 64), 256, 0, stream>>>(hbf, WTqkv, MM, 2304, CC,
        qb, kb, vb, bq, bk, bv, nullptr, nullptr);
    attn_k<<<BB * HH * (TT / 4), 256, 0, stream>>>(qb, kb, vb, attnb);
    gemm_bf16<2><<<dim3(6, 64), 256, 0, stream>>>(attnb, WTp, MM, CC, CC,
        out, nullptr, nullptr, bp, nullptr, nullptr, x, nullptr);

    // --- MLP sublayer ---
    ln_k<<<MM, 256, 0, stream>>>(out, g2, be2, hbf);
    gemm_bf16<3><<<dim3(24, 64), 256, 0, stream>>>(hbf, WT1, MM, C4, CC,
        nullptr, nullptr, nullptr, b1, nullptr, nullptr, nullptr, midb);
    gemm_bf16<2><<<dim3(6, 64), 256, 0, stream>>>(midb, WT2, MM, CC, C4,
        out, nullptr, nullptr, b2, nullptr, nullptr, out, nullptr);
}

// Round 3
// 427.051 us; speedup vs baseline: 11.0396x; 6.6236x over previous
//
#include <hip/hip_runtime.h>
#include <hip/hip_bf16.h>
#include <math.h>

#define BB 4
#define TT 2048
#define CC 768
#define HH 12
#define HDIM 64
#define C4 3072
#define MM (BB*TT)   // 8192 rows
#define EPSL 1e-5f

typedef __bf16 bf16x8 __attribute__((ext_vector_type(8)));
typedef float f32x4 __attribute__((ext_vector_type(4)));

__device__ __forceinline__ ushort f2bf(float f) {
    union { float f; unsigned u; } v; v.f = f;
    unsigned r = v.u + 0x7fffu + ((v.u >> 16) & 1u);
    return (ushort)(r >> 16);
}

__device__ __forceinline__ void glds16(const void* g, void* l) {
    __builtin_amdgcn_global_load_lds(
        (const __attribute__((address_space(1))) void*)g,
        (__attribute__((address_space(3))) void*)l, 16, 0, 0);
}

// ---------------------------------------------------------------------------
// LayerNorm: one block per row, fp32 in -> bf16 out
// ---------------------------------------------------------------------------
__global__ __launch_bounds__(256) void ln_k(const float* __restrict__ X,
                                            const float* __restrict__ G,
                                            const float* __restrict__ Be,
                                            ushort* __restrict__ O)
{
    int row = blockIdx.x;
    const float* xr = X + (size_t)row * CC;
    int t = threadIdx.x;
    float v0 = xr[t], v1 = xr[t + 256], v2 = xr[t + 512];
    float s  = v0 + v1 + v2;
    float sq = v0*v0 + v1*v1 + v2*v2;
    #pragma unroll
    for (int off = 32; off; off >>= 1) {
        s  += __shfl_xor(s,  off);
        sq += __shfl_xor(sq, off);
    }
    __shared__ float red[8];
    int wv = t >> 6, ln = t & 63;
    if (ln == 0) { red[wv] = s; red[4 + wv] = sq; }
    __syncthreads();
    s  = red[0] + red[1] + red[2] + red[3];
    sq = red[4] + red[5] + red[6] + red[7];
    float mu  = s * (1.0f / CC);
    float var = sq * (1.0f / CC) - mu * mu;
    float rs  = rsqrtf(var + EPSL);
    ushort* orow = O + (size_t)row * CC;
    orow[t]       = f2bf((v0 - mu) * rs * G[t]       + Be[t]);
    orow[t + 256] = f2bf((v1 - mu) * rs * G[t + 256] + Be[t + 256]);
    orow[t + 512] = f2bf((v2 - mu) * rs * G[t + 512] + Be[t + 512]);
}

// ---------------------------------------------------------------------------
// Weight repack: fp32 W -> bf16 W^T [N][K] via 64x64 LDS transpose tile.
// MODE 0: W row-major [K,N].  MODE 1: W per-head [H][768][64] (wq/wk/wv).
// ---------------------------------------------------------------------------
template<int MODE>
__global__ __launch_bounds__(256) void repack_k(const float* __restrict__ W,
                                                ushort* __restrict__ WT,
                                                int K, int N, int outStride)
{
    __shared__ float tl[64][65];
    int n0 = blockIdx.x * 64, k0 = blockIdx.y * 64;
    int c = threadIdx.x & 63, rr = threadIdx.x >> 6;
    #pragma unroll
    for (int i = 0; i < 16; ++i) {
        int r = i * 4 + rr;
        float v;
        if (MODE == 0) v = W[(size_t)(k0 + r) * N + n0 + c];
        else           v = W[((size_t)(n0 >> 6) * CC + k0 + r) * 64 + c];
        tl[r][c] = v;
    }
    __syncthreads();
    #pragma unroll
    for (int i = 0; i < 16; ++i) {
        int r = i * 4 + rr;   // n within tile
        WT[(size_t)(n0 + r) * outStride + k0 + c] = f2bf(tl[c][r]);
    }
}

// ---------------------------------------------------------------------------
// bf16 MFMA GEMM (m97 structure): C[M,N] = A[M,K] @ BT[N,K]^T, fp32 accum.
// EPI 1: QKV -> bf16 q/k/v in [B][H][T][64] (+per-segment bias)
// EPI 2: f32 out = acc + bias + resid
// EPI 3: bf16 out = relu(acc + bias)
// ---------------------------------------------------------------------------
template<int EPI>
__global__ __launch_bounds__(256) void gemm_bf16(
    const ushort* __restrict__ A, const ushort* __restrict__ BT,
    int M, int N, int K,
    void* __restrict__ ov0, void* __restrict__ ov1, void* __restrict__ ov2,
    const float* __restrict__ bias0, const float* __restrict__ bias1,
    const float* __restrict__ bias2,
    const float* __restrict__ resid, ushort* __restrict__ obf)
{
    __shared__ ushort Al[128 * 32];
    __shared__ ushort Bl[128 * 32];
    int bn = blockIdx.x, bm = blockIdx.y;
    int tid = threadIdx.x;
    int lane = tid & 63;
    int w = tid >> 6;
    int wr = (w >> 1) * 64, wc = (w & 1) * 64;
    int fr = lane & 15, kh = lane >> 4;

    f32x4 acc[4][4] = {};

    const size_t aRow = (size_t)bm * 128;
    const size_t bRow = (size_t)bn * 128;

    for (int k0 = 0; k0 < K; k0 += 32) {
        #pragma unroll
        for (int r = 0; r < 2; ++r) {
            int e = r * 256 + tid;
            glds16(A  + (aRow + (e >> 2)) * K + k0 + (e & 3) * 8, Al + e * 8);
            glds16(BT + (bRow + (e >> 2)) * K + k0 + (e & 3) * 8, Bl + e * 8);
        }
        __syncthreads();
        bf16x8 av[4], bv[4];
        #pragma unroll
        for (int i = 0; i < 4; ++i)
            av[i] = *(const bf16x8*)&Al[(wr + i * 16 + fr) * 32 + kh * 8];
        #pragma unroll
        for (int i = 0; i < 4; ++i)
            bv[i] = *(const bf16x8*)&Bl[(wc + i * 16 + fr) * 32 + kh * 8];
        #pragma unroll
        for (int i = 0; i < 4; ++i)
            #pragma unroll
            for (int j = 0; j < 4; ++j)
                acc[i][j] = __builtin_amdgcn_mfma_f32_16x16x32_bf16(av[i], bv[j], acc[i][j], 0, 0, 0);
        __syncthreads();
    }

    // C/D layout (m89-verified): col = lane&15, row = (lane>>4)*4 + r
    if (EPI == 1) {
        int seg = (bn * 128) / CC;
        ushort* op = (ushort*)(seg == 0 ? ov0 : (seg == 1 ? ov1 : ov2));
        const float* bsp = seg == 0 ? bias0 : (seg == 1 ? bias1 : bias2);
        int cb = bn * 128 - seg * CC + wc;   // multiple of 64
        int h = cb >> 6;
        #pragma unroll
        for (int i = 0; i < 4; ++i) {
            int row0 = bm * 128 + wr + i * 16 + kh * 4;
            int b = row0 >> 11;
            int t0 = row0 & (TT - 1);
            #pragma unroll
            for (int j = 0; j < 4; ++j) {
                int col = cb + j * 16 + fr;
                int d = col & 63;
                float bsv = bsp[col];
                #pragma unroll
                for (int r = 0; r < 4; ++r)
                    op[((size_t)(b * HH + h) * TT + t0 + r) * 64 + d] =
                        f2bf(acc[i][j][r] + bsv);
            }
        }
    } else if (EPI == 2) {
        float* o0 = (float*)ov0;
        int cb = bn * 128 + wc;
        #pragma unroll
        for (int i = 0; i < 4; ++i) {
            int row0 = bm * 128 + wr + i * 16 + kh * 4;
            #pragma unroll
            for (int j = 0; j < 4; ++j) {
                int col = cb + j * 16 + fr;
                float bsv = bias0[col];
                #pragma unroll
                for (int r = 0; r < 4; ++r) {
                    size_t idx = (size_t)(row0 + r) * N + col;
                    o0[idx] = acc[i][j][r] + bsv + resid[idx];
                }
            }
        }
    } else {  // EPI 3
        int cb = bn * 128 + wc;
        #pragma unroll
        for (int i = 0; i < 4; ++i) {
            int row0 = bm * 128 + wr + i * 16 + kh * 4;
            #pragma unroll
            for (int j = 0; j < 4; ++j) {
                int col = cb + j * 16 + fr;
                float bsv = bias0[col];
                #pragma unroll
                for (int r = 0; r < 4; ++r) {
                    float v = fmaxf(acc[i][j][r] + bsv, 0.f);
                    obf[(size_t)(row0 + r) * N + col] = f2bf(v);
                }
            }
        }
    }
}

// ---------------------------------------------------------------------------
// V transpose: bf16 [B,H,T,64] -> [B,H,64,T] (per (b,h), 64x64 LDS tiles)
// ---------------------------------------------------------------------------
__global__ __launch_bounds__(256) void vtrans_k(const ushort* __restrict__ V,
                                                ushort* __restrict__ Vt)
{
    __shared__ ushort tl[64][72];
    int blk = blockIdx.x;
    int tt = blk & 31, bh = blk >> 5;
    size_t base = (size_t)bh * TT * 64;
    int t0 = tt * 64;
    int e = threadIdx.x;
    int rr = e >> 3, cc8 = (e & 7) * 8;
    #pragma unroll
    for (int p = 0; p < 2; ++p) {
        int t = p * 32 + rr;
        *(uint4*)&tl[t][cc8] = *(const uint4*)&V[base + (size_t)(t0 + t) * 64 + cc8];
    }
    __syncthreads();
    #pragma unroll
    for (int p = 0; p < 2; ++p) {
        int d = p * 32 + rr;
        ushort tmp[8];
        #pragma unroll
        for (int i = 0; i < 8; ++i) tmp[i] = tl[cc8 + i][d];
        *(uint4*)&Vt[base + (size_t)d * TT + t0 + cc8] = *(uint4*)tmp;
    }
}

// ---------------------------------------------------------------------------
// Flash attention, bf16 MFMA. Block = 64 q rows (4 waves x 16), KV tiles = 64.
// Q/K bf16 [B,H,T,64]; V^T bf16 [B,H,64,T]; out bf16 [B,T,C]. No 1/sqrt(d)
// scaling (matches reference). LDS rows padded to 72 (2-way = free).
// ---------------------------------------------------------------------------
__global__ __launch_bounds__(256) void attn_k(const ushort* __restrict__ Q,
                                              const ushort* __restrict__ Kb,
                                              const ushort* __restrict__ Vt,
                                              ushort* __restrict__ Ob)
{
    __shared__ ushort Kl[64][72];
    __shared__ ushort Vl[64][72];
    __shared__ ushort Pl[4][16][72];

    int blk = blockIdx.x;
    int qt = blk & 31;
    int bh = blk >> 5;
    int b = bh / HH, h = bh - b * HH;
    int q0 = qt * 64;
    int tid = threadIdx.x, lane = tid & 63, w = tid >> 6;
    int c = lane & 15, g = lane >> 4;
    size_t base = (size_t)bh * TT * 64;

    // wave's Q A-fragments (16 rows x 64 d), kept in registers
    bf16x8 aq[2];
    #pragma unroll
    for (int kc = 0; kc < 2; ++kc)
        aq[kc] = *(const bf16x8*)&Q[base + (size_t)(q0 + w * 16 + c) * 64 + kc * 32 + g * 8];

    f32x4 oa[4] = {};
    float mrun[4] = {-INFINITY, -INFINITY, -INFINITY, -INFINITY};
    float lrun[4] = {0.f, 0.f, 0.f, 0.f};

    int srow = tid >> 3, scol = (tid & 7) * 8;

    for (int kv0 = 0; kv0 <= q0; kv0 += 64) {
        __syncthreads();
        #pragma unroll
        for (int p = 0; p < 2; ++p) {
            int r = p * 32 + srow;
            *(uint4*)&Kl[r][scol] = *(const uint4*)&Kb[base + (size_t)(kv0 + r) * 64 + scol];
            *(uint4*)&Vl[r][scol] = *(const uint4*)&Vt[base + (size_t)r * TT + kv0 + scol];
        }
        __syncthreads();

        // S[16 q][64 kv] = Q @ K^T
        f32x4 sa[4] = {};
        #pragma unroll
        for (int kc = 0; kc < 2; ++kc)
            #pragma unroll
            for (int j = 0; j < 4; ++j) {
                bf16x8 kf = *(const bf16x8*)&Kl[j * 16 + c][kc * 32 + g * 8];
                sa[j] = __builtin_amdgcn_mfma_f32_16x16x32_bf16(aq[kc], kf, sa[j], 0, 0, 0);
            }

        if (kv0 == q0) {   // diagonal tile: causal mask
            #pragma unroll
            for (int j = 0; j < 4; ++j)
                #pragma unroll
                for (int r = 0; r < 4; ++r)
                    if (j * 16 + c > w * 16 + g * 4 + r) sa[j][r] = -1e30f;
        }

        // online softmax; row = (g*4+r), kv lanes are the low-4 lane bits
        #pragma unroll
        for (int r = 0; r < 4; ++r) {
            float mx = fmaxf(fmaxf(sa[0][r], sa[1][r]), fmaxf(sa[2][r], sa[3][r]));
            #pragma unroll
            for (int off = 8; off; off >>= 1) mx = fmaxf(mx, __shfl_xor(mx, off));
            float mnew = fmaxf(mrun[r], mx);
            float sc = __expf(mrun[r] - mnew);   // first tile: exp(-inf)=0
            float ps = 0.f;
            #pragma unroll
            for (int j = 0; j < 4; ++j) {
                float p = __expf(sa[j][r] - mnew);
                sa[j][r] = p;
                ps += p;
            }
            #pragma unroll
            for (int off = 8; off; off >>= 1) ps += __shfl_xor(ps, off);
            lrun[r] = lrun[r] * sc + ps;
            mrun[r] = mnew;
            #pragma unroll
            for (int j = 0; j < 4; ++j) oa[j][r] *= sc;
        }

        // P -> bf16 -> per-wave LDS (reshape C/D layout -> A-frag layout)
        #pragma unroll
        for (int r = 0; r < 4; ++r)
            #pragma unroll
            for (int j = 0; j < 4; ++j)
                Pl[w][g * 4 + r][j * 16 + c] = f2bf(sa[j][r]);

        bf16x8 pf[2];
        #pragma unroll
        for (int kc = 0; kc < 2; ++kc)
            pf[kc] = *(const bf16x8*)&Pl[w][c][kc * 32 + g * 8];

        // O[16 q][64 d] += P @ V  (B^T rows = V^T rows = d)
        #pragma unroll
        for (int kc = 0; kc < 2; ++kc)
            #pragma unroll
            for (int j = 0; j < 4; ++j) {
                bf16x8 vf = *(const bf16x8*)&Vl[j * 16 + c][kc * 32 + g * 8];
                oa[j] = __builtin_amdgcn_mfma_f32_16x16x32_bf16(pf[kc], vf, oa[j], 0, 0, 0);
            }
    }

    size_t orow = (size_t)b * TT + q0 + w * 16;
    #pragma unroll
    for (int j = 0; j < 4; ++j)
        #pragma unroll
        for (int r = 0; r < 4; ++r) {
            float v = oa[j][r] / lrun[r];
            Ob[(orow + g * 4 + r) * CC + h * 64 + j * 16 + c] = f2bf(v);
        }
}

// ---------------------------------------------------------------------------
// Orchestration. ws layout (ushorts), S = MM*CC = 6291456:
//   WTqkv [2304*768]  WTp [768*768]  WT1 [3072*768]  WT2 [768*3072]
//   hbf [S]  attnb [S]  qb [S]  kb [S]  vb [S]  vtb [S]
//   midb [MM*3072] aliases qb..vtb exactly (dead after attention)
// Total ~89.7 MB.
// ---------------------------------------------------------------------------
extern "C" void kernel_launch(void* const* d_in, const int* in_sizes, int n_in,
                              void* d_out, int out_size, void* d_ws, size_t ws_size,
                              hipStream_t stream)
{
    const float* x   = (const float*)d_in[0];
    const float* wq  = (const float*)d_in[1];
    const float* bq  = (const float*)d_in[2];
    const float* wk  = (const float*)d_in[3];
    const float* bk  = (const float*)d_in[4];
    const float* wvw = (const float*)d_in[5];
    const float* bv  = (const float*)d_in[6];
    const float* wp  = (const float*)d_in[7];
    const float* bp  = (const float*)d_in[8];
    const float* w1  = (const float*)d_in[9];
    const float* b1  = (const float*)d_in[10];
    const float* w2  = (const float*)d_in[11];
    const float* b2  = (const float*)d_in[12];
    const float* g1  = (const float*)d_in[13];
    const float* be1 = (const float*)d_in[14];
    const float* g2  = (const float*)d_in[15];
    const float* be2 = (const float*)d_in[16];

    float* out = (float*)d_out;
    const size_t S = (size_t)MM * CC;

    ushort* wsu   = (ushort*)d_ws;
    ushort* WTqkv = wsu;
    ushort* WTp   = WTqkv + (size_t)2304 * 768;
    ushort* WT1   = WTp   + (size_t)768 * 768;
    ushort* WT2   = WT1   + (size_t)3072 * 768;
    ushort* hbf   = WT2   + (size_t)768 * 3072;
    ushort* attnb = hbf   + S;
    ushort* qb    = attnb + S;
    ushort* kb    = qb + S;
    ushort* vb    = kb + S;
    ushort* vtb   = vb + S;
    ushort* midb  = qb;   // [8192][3072] bf16 == qb..vtb exactly

    dim3 rg(12, 12);
    repack_k<1><<<rg, 256, 0, stream>>>(wq,  WTqkv,                      768, 768, 768);
    repack_k<1><<<rg, 256, 0, stream>>>(wk,  WTqkv + (size_t)768*768,    768, 768, 768);
    repack_k<1><<<rg, 256, 0, stream>>>(wvw, WTqkv + (size_t)2*768*768,  768, 768, 768);
    repack_k<0><<<rg, 256, 0, stream>>>(wp,  WTp, 768, 768, 768);
    repack_k<0><<<dim3(48, 12), 256, 0, stream>>>(w1, WT1, 768, 3072, 768);
    repack_k<0><<<dim3(12, 48), 256, 0, stream>>>(w2, WT2, 3072, 768, 3072);

    // --- attention sublayer ---
    ln_k<<<MM, 256, 0, stream>>>(x, g1, be1, hbf);
    gemm_bf16<1><<<dim3(18, 64), 256, 0, stream>>>(hbf, WTqkv, MM, 2304, CC,
        qb, kb, vb, bq, bk, bv, nullptr, nullptr);
    vtrans_k<<<48 * 32, 256, 0, stream>>>(vb, vtb);
    attn_k<<<48 * 32, 256, 0, stream>>>(qb, kb, vtb, attnb);
    gemm_bf16<2><<<dim3(6, 64), 256, 0, stream>>>(attnb, WTp, MM, CC, CC,
        out, nullptr, nullptr, bp, nullptr, nullptr, x, nullptr);

    // --- MLP sublayer ---
    ln_k<<<MM, 256, 0, stream>>>(out, g2, be2, hbf);
    gemm_bf16<3><<<dim3(24, 64), 256, 0, stream>>>(hbf, WT1, MM, C4, CC,
        nullptr, nullptr, nullptr, b1, nullptr, nullptr, nullptr, midb);
    gemm_bf16<2><<<dim3(6, 64), 256, 0, stream>>>(midb, WT2, MM, CC, C4,
        out, nullptr, nullptr, b2, nullptr, nullptr, out, nullptr);
}

// Round 4
// 342.358 us; speedup vs baseline: 13.7706x; 1.2474x over previous
//
#include <hip/hip_runtime.h>
#include <hip/hip_bf16.h>
#include <math.h>

#define BB 4
#define TT 2048
#define CC 768
#define HH 12
#define HDIM 64
#define C4 3072
#define MM (BB*TT)   // 8192 rows
#define EPSL 1e-5f

typedef __bf16 bf16x8 __attribute__((ext_vector_type(8)));
typedef float f32x4 __attribute__((ext_vector_type(4)));

__device__ __forceinline__ ushort f2bf(float f) {
    union { float f; unsigned u; } v; v.f = f;
    unsigned r = v.u + 0x7fffu + ((v.u >> 16) & 1u);
    return (ushort)(r >> 16);
}

__device__ __forceinline__ void glds16(const void* g, void* l) {
    __builtin_amdgcn_global_load_lds(
        (const __attribute__((address_space(1))) void*)g,
        (__attribute__((address_space(3))) void*)l, 16, 0, 0);
}

// ---------------------------------------------------------------------------
// LayerNorm: one block per row, fp32 in -> bf16 out
// ---------------------------------------------------------------------------
__global__ __launch_bounds__(256) void ln_k(const float* __restrict__ X,
                                            const float* __restrict__ G,
                                            const float* __restrict__ Be,
                                            ushort* __restrict__ O)
{
    int row = blockIdx.x;
    const float* xr = X + (size_t)row * CC;
    int t = threadIdx.x;
    float v0 = xr[t], v1 = xr[t + 256], v2 = xr[t + 512];
    float s  = v0 + v1 + v2;
    float sq = v0*v0 + v1*v1 + v2*v2;
    #pragma unroll
    for (int off = 32; off; off >>= 1) {
        s  += __shfl_xor(s,  off);
        sq += __shfl_xor(sq, off);
    }
    __shared__ float red[8];
    int wv = t >> 6, ln = t & 63;
    if (ln == 0) { red[wv] = s; red[4 + wv] = sq; }
    __syncthreads();
    s  = red[0] + red[1] + red[2] + red[3];
    sq = red[4] + red[5] + red[6] + red[7];
    float mu  = s * (1.0f / CC);
    float var = sq * (1.0f / CC) - mu * mu;
    float rs  = rsqrtf(var + EPSL);
    ushort* orow = O + (size_t)row * CC;
    orow[t]       = f2bf((v0 - mu) * rs * G[t]       + Be[t]);
    orow[t + 256] = f2bf((v1 - mu) * rs * G[t + 256] + Be[t + 256]);
    orow[t + 512] = f2bf((v2 - mu) * rs * G[t + 512] + Be[t + 512]);
}

// ---------------------------------------------------------------------------
// Weight repack: fp32 W -> bf16 W^T [N][K] via 64x64 LDS transpose tile.
// MODE 0: W row-major [K,N].  MODE 1: W per-head [H][768][64] (wq/wk/wv).
// ---------------------------------------------------------------------------
template<int MODE>
__global__ __launch_bounds__(256) void repack_k(const float* __restrict__ W,
                                                ushort* __restrict__ WT,
                                                int K, int N, int outStride)
{
    __shared__ float tl[64][65];
    int n0 = blockIdx.x * 64, k0 = blockIdx.y * 64;
    int c = threadIdx.x & 63, rr = threadIdx.x >> 6;
    #pragma unroll
    for (int i = 0; i < 16; ++i) {
        int r = i * 4 + rr;
        float v;
        if (MODE == 0) v = W[(size_t)(k0 + r) * N + n0 + c];
        else           v = W[((size_t)(n0 >> 6) * CC + k0 + r) * 64 + c];
        tl[r][c] = v;
    }
    __syncthreads();
    #pragma unroll
    for (int i = 0; i < 16; ++i) {
        int r = i * 4 + rr;   // n within tile
        WT[(size_t)(n0 + r) * outStride + k0 + c] = f2bf(tl[c][r]);
    }
}

// ---------------------------------------------------------------------------
// bf16 MFMA GEMM (m97 structure): C[M,N] = A[M,K] @ BT[N,K]^T, fp32 accum.
// EPI 1: QKV -> bf16 q/k/v in [B][H][T][64] (+per-segment bias)
// EPI 2: f32 out = acc + bias + resid
// EPI 3: bf16 out = relu(acc + bias)
// ---------------------------------------------------------------------------
template<int EPI>
__global__ __launch_bounds__(256) void gemm_bf16(
    const ushort* __restrict__ A, const ushort* __restrict__ BT,
    int M, int N, int K,
    void* __restrict__ ov0, void* __restrict__ ov1, void* __restrict__ ov2,
    const float* __restrict__ bias0, const float* __restrict__ bias1,
    const float* __restrict__ bias2,
    const float* __restrict__ resid, ushort* __restrict__ obf)
{
    __shared__ ushort Al[128 * 32];
    __shared__ ushort Bl[128 * 32];
    int bn = blockIdx.x, bm = blockIdx.y;
    int tid = threadIdx.x;
    int lane = tid & 63;
    int w = tid >> 6;
    int wr = (w >> 1) * 64, wc = (w & 1) * 64;
    int fr = lane & 15, kh = lane >> 4;

    f32x4 acc[4][4] = {};

    const size_t aRow = (size_t)bm * 128;
    const size_t bRow = (size_t)bn * 128;

    for (int k0 = 0; k0 < K; k0 += 32) {
        #pragma unroll
        for (int r = 0; r < 2; ++r) {
            int e = r * 256 + tid;
            glds16(A  + (aRow + (e >> 2)) * K + k0 + (e & 3) * 8, Al + e * 8);
            glds16(BT + (bRow + (e >> 2)) * K + k0 + (e & 3) * 8, Bl + e * 8);
        }
        __syncthreads();
        bf16x8 av[4], bv[4];
        #pragma unroll
        for (int i = 0; i < 4; ++i)
            av[i] = *(const bf16x8*)&Al[(wr + i * 16 + fr) * 32 + kh * 8];
        #pragma unroll
        for (int i = 0; i < 4; ++i)
            bv[i] = *(const bf16x8*)&Bl[(wc + i * 16 + fr) * 32 + kh * 8];
        #pragma unroll
        for (int i = 0; i < 4; ++i)
            #pragma unroll
            for (int j = 0; j < 4; ++j)
                acc[i][j] = __builtin_amdgcn_mfma_f32_16x16x32_bf16(av[i], bv[j], acc[i][j], 0, 0, 0);
        __syncthreads();
    }

    // C/D layout (m89-verified): col = lane&15, row = (lane>>4)*4 + r
    if (EPI == 1) {
        int seg = (bn * 128) / CC;
        ushort* op = (ushort*)(seg == 0 ? ov0 : (seg == 1 ? ov1 : ov2));
        const float* bsp = seg == 0 ? bias0 : (seg == 1 ? bias1 : bias2);
        int cb = bn * 128 - seg * CC + wc;   // multiple of 64
        int h = cb >> 6;
        #pragma unroll
        for (int i = 0; i < 4; ++i) {
            int row0 = bm * 128 + wr + i * 16 + kh * 4;
            int b = row0 >> 11;
            int t0 = row0 & (TT - 1);
            #pragma unroll
            for (int j = 0; j < 4; ++j) {
                int col = cb + j * 16 + fr;
                int d = col & 63;
                float bsv = bsp[col];
                #pragma unroll
                for (int r = 0; r < 4; ++r)
                    op[((size_t)(b * HH + h) * TT + t0 + r) * 64 + d] =
                        f2bf(acc[i][j][r] + bsv);
            }
        }
    } else if (EPI == 2) {
        float* o0 = (float*)ov0;
        int cb = bn * 128 + wc;
        #pragma unroll
        for (int i = 0; i < 4; ++i) {
            int row0 = bm * 128 + wr + i * 16 + kh * 4;
            #pragma unroll
            for (int j = 0; j < 4; ++j) {
                int col = cb + j * 16 + fr;
                float bsv = bias0[col];
                #pragma unroll
                for (int r = 0; r < 4; ++r) {
                    size_t idx = (size_t)(row0 + r) * N + col;
                    o0[idx] = acc[i][j][r] + bsv + resid[idx];
                }
            }
        }
    } else {  // EPI 3
        int cb = bn * 128 + wc;
        #pragma unroll
        for (int i = 0; i < 4; ++i) {
            int row0 = bm * 128 + wr + i * 16 + kh * 4;
            #pragma unroll
            for (int j = 0; j < 4; ++j) {
                int col = cb + j * 16 + fr;
                float bsv = bias0[col];
                #pragma unroll
                for (int r = 0; r < 4; ++r) {
                    float v = fmaxf(acc[i][j][r] + bsv, 0.f);
                    obf[(size_t)(row0 + r) * N + col] = f2bf(v);
                }
            }
        }
    }
}

// ---------------------------------------------------------------------------
// V transpose: bf16 [B,H,T,64] -> [B,H,64,T] (per (b,h), 64x64 LDS tiles)
// ---------------------------------------------------------------------------
__global__ __launch_bounds__(256) void vtrans_k(const ushort* __restrict__ V,
                                                ushort* __restrict__ Vt)
{
    __shared__ ushort tl[64][72];
    int blk = blockIdx.x;
    int tt = blk & 31, bh = blk >> 5;
    size_t base = (size_t)bh * TT * 64;
    int t0 = tt * 64;
    int e = threadIdx.x;
    int rr = e >> 3, cc8 = (e & 7) * 8;
    #pragma unroll
    for (int p = 0; p < 2; ++p) {
        int t = p * 32 + rr;
        *(uint4*)&tl[t][cc8] = *(const uint4*)&V[base + (size_t)(t0 + t) * 64 + cc8];
    }
    __syncthreads();
    #pragma unroll
    for (int p = 0; p < 2; ++p) {
        int d = p * 32 + rr;
        ushort tmp[8];
        #pragma unroll
        for (int i = 0; i < 8; ++i) tmp[i] = tl[cc8 + i][d];
        *(uint4*)&Vt[base + (size_t)d * TT + t0 + cc8] = *(uint4*)tmp;
    }
}

// ---------------------------------------------------------------------------
// Flash attention, bf16 MFMA, work-balanced. One block = q-tile PAIR
// (i, 31-i): every block does exactly 33 KV tiles (no tail imbalance).
// 4 waves x 16 q rows per tile. Q pre-scaled by log2(e) so softmax runs in
// exp2 domain (v_exp_f32 native). Sum-reduce deferred to the end (per-lane
// partials; linearity). T13 defer-max skips rescale when max growth <= 11.5
// (= 8 nats). No 1/sqrt(d) scaling (matches reference).
// ---------------------------------------------------------------------------
__global__ __launch_bounds__(256) void attn_k(const ushort* __restrict__ Q,
                                              const ushort* __restrict__ Kb,
                                              const ushort* __restrict__ Vt,
                                              ushort* __restrict__ Ob)
{
    __shared__ ushort Kl[64][72];
    __shared__ ushort Vl[64][72];
    __shared__ ushort Pl[4][16][72];

    int blk = blockIdx.x;
    int pair = blk & 15;
    int bh = blk >> 4;
    int b = bh / HH, h = bh - b * HH;
    int tid = threadIdx.x, lane = tid & 63, w = tid >> 6;
    int c = lane & 15, g = lane >> 4;
    size_t base = (size_t)bh * TT * 64;
    int srow = tid >> 3, scol = (tid & 7) * 8;
    const float LOG2E = 1.44269504088896340736f;

    #pragma unroll
    for (int sel = 0; sel < 2; ++sel) {
        int qt = sel ? (31 - pair) : pair;
        int q0 = qt * 64;

        // wave's Q A-fragments (16 rows x 64 d), scaled by log2e, in regs
        bf16x8 aq[2];
        #pragma unroll
        for (int kc = 0; kc < 2; ++kc) {
            bf16x8 raw = *(const bf16x8*)&Q[base + (size_t)(q0 + w * 16 + c) * 64 + kc * 32 + g * 8];
            #pragma unroll
            for (int e = 0; e < 8; ++e)
                raw[e] = (__bf16)((float)raw[e] * LOG2E);
            aq[kc] = raw;
        }

        f32x4 oa[4] = {};
        float mrun[4] = {-INFINITY, -INFINITY, -INFINITY, -INFINITY};
        float lrun[4] = {0.f, 0.f, 0.f, 0.f};

        for (int kv0 = 0; kv0 <= q0; kv0 += 64) {
            __syncthreads();
            #pragma unroll
            for (int p = 0; p < 2; ++p) {
                int r = p * 32 + srow;
                *(uint4*)&Kl[r][scol] = *(const uint4*)&Kb[base + (size_t)(kv0 + r) * 64 + scol];
                *(uint4*)&Vl[r][scol] = *(const uint4*)&Vt[base + (size_t)r * TT + kv0 + scol];
            }
            __syncthreads();

            // S[16 q][64 kv] = Qs @ K^T  (log2-domain scores)
            f32x4 sa[4] = {};
            #pragma unroll
            for (int kc = 0; kc < 2; ++kc)
                #pragma unroll
                for (int j = 0; j < 4; ++j) {
                    bf16x8 kf = *(const bf16x8*)&Kl[j * 16 + c][kc * 32 + g * 8];
                    sa[j] = __builtin_amdgcn_mfma_f32_16x16x32_bf16(aq[kc], kf, sa[j], 0, 0, 0);
                }

            if (kv0 == q0) {   // diagonal tile: causal mask
                #pragma unroll
                for (int j = 0; j < 4; ++j)
                    #pragma unroll
                    for (int r = 0; r < 4; ++r)
                        if (j * 16 + c > w * 16 + g * 4 + r) sa[j][r] = -1e30f;
            }

            // row maxes (row = g*4+r; row-mates differ in low-4 lane bits)
            float mx[4];
            #pragma unroll
            for (int r = 0; r < 4; ++r) {
                float m0 = fmaxf(fmaxf(sa[0][r], sa[1][r]), fmaxf(sa[2][r], sa[3][r]));
                #pragma unroll
                for (int off = 8; off; off >>= 1) m0 = fmaxf(m0, __shfl_xor(m0, off));
                mx[r] = m0;
            }
            float need = fmaxf(fmaxf(mx[0] - mrun[0], mx[1] - mrun[1]),
                               fmaxf(mx[2] - mrun[2], mx[3] - mrun[3]));
            if (!__all(need <= 11.5f)) {   // T13: rescale only on real growth
                #pragma unroll
                for (int r = 0; r < 4; ++r) {
                    float mnew = fmaxf(mrun[r], mx[r]);
                    float sc = __builtin_amdgcn_exp2f(mrun[r] - mnew);
                    lrun[r] *= sc;
                    #pragma unroll
                    for (int j = 0; j < 4; ++j) oa[j][r] *= sc;
                    mrun[r] = mnew;
                }
            }
            // exps + per-lane partial sums (no cross-lane reduce here)
            #pragma unroll
            for (int r = 0; r < 4; ++r) {
                float ps = 0.f;
                #pragma unroll
                for (int j = 0; j < 4; ++j) {
                    float p = __builtin_amdgcn_exp2f(sa[j][r] - mrun[r]);
                    sa[j][r] = p;
                    ps += p;
                }
                lrun[r] += ps;
            }

            // P -> bf16 -> per-wave LDS (C/D layout -> A-frag layout)
            #pragma unroll
            for (int r = 0; r < 4; ++r)
                #pragma unroll
                for (int j = 0; j < 4; ++j)
                    Pl[w][g * 4 + r][j * 16 + c] = f2bf(sa[j][r]);

            bf16x8 pf[2];
            #pragma unroll
            for (int kc = 0; kc < 2; ++kc)
                pf[kc] = *(const bf16x8*)&Pl[w][c][kc * 32 + g * 8];

            // O[16 q][64 d] += P @ V
            #pragma unroll
            for (int kc = 0; kc < 2; ++kc)
                #pragma unroll
                for (int j = 0; j < 4; ++j) {
                    bf16x8 vf = *(const bf16x8*)&Vl[j * 16 + c][kc * 32 + g * 8];
                    oa[j] = __builtin_amdgcn_mfma_f32_16x16x32_bf16(pf[kc], vf, oa[j], 0, 0, 0);
                }
        }

        // final row-sum of deferred partials, then normalize + store
        float inv[4];
        #pragma unroll
        for (int r = 0; r < 4; ++r) {
            float l = lrun[r];
            #pragma unroll
            for (int off = 8; off; off >>= 1) l += __shfl_xor(l, off);
            inv[r] = 1.0f / l;
        }
        size_t orow = (size_t)b * TT + q0 + w * 16;
        #pragma unroll
        for (int j = 0; j < 4; ++j)
            #pragma unroll
            for (int r = 0; r < 4; ++r) {
                float v = oa[j][r] * inv[r];
                Ob[(orow + g * 4 + r) * CC + h * 64 + j * 16 + c] = f2bf(v);
            }
    }
}

// ---------------------------------------------------------------------------
// Orchestration. ws layout (ushorts), S = MM*CC = 6291456:
//   WTqkv [2304*768]  WTp [768*768]  WT1 [3072*768]  WT2 [768*3072]
//   hbf [S]  attnb [S]  qb [S]  kb [S]  vb [S]  vtb [S]
//   midb [MM*3072] aliases qb..vtb exactly (dead after attention)
// Total ~89.7 MB.
// ---------------------------------------------------------------------------
extern "C" void kernel_launch(void* const* d_in, const int* in_sizes, int n_in,
                              void* d_out, int out_size, void* d_ws, size_t ws_size,
                              hipStream_t stream)
{
    const float* x   = (const float*)d_in[0];
    const float* wq  = (const float*)d_in[1];
    const float* bq  = (const float*)d_in[2];
    const float* wk  = (const float*)d_in[3];
    const float* bk  = (const float*)d_in[4];
    const float* wvw = (const float*)d_in[5];
    const float* bv  = (const float*)d_in[6];
    const float* wp  = (const float*)d_in[7];
    const float* bp  = (const float*)d_in[8];
    const float* w1  = (const float*)d_in[9];
    const float* b1  = (const float*)d_in[10];
    const float* w2  = (const float*)d_in[11];
    const float* b2  = (const float*)d_in[12];
    const float* g1  = (const float*)d_in[13];
    const float* be1 = (const float*)d_in[14];
    const float* g2  = (const float*)d_in[15];
    const float* be2 = (const float*)d_in[16];

    float* out = (float*)d_out;
    const size_t S = (size_t)MM * CC;

    ushort* wsu   = (ushort*)d_ws;
    ushort* WTqkv = wsu;
    ushort* WTp   = WTqkv + (size_t)2304 * 768;
    ushort* WT1   = WTp   + (size_t)768 * 768;
    ushort* WT2   = WT1   + (size_t)3072 * 768;
    ushort* hbf   = WT2   + (size_t)768 * 3072;
    ushort* attnb = hbf   + S;
    ushort* qb    = attnb + S;
    ushort* kb    = qb + S;
    ushort* vb    = kb + S;
    ushort* vtb   = vb + S;
    ushort* midb  = qb;   // [8192][3072] bf16 == qb..vtb exactly

    dim3 rg(12, 12);
    repack_k<1><<<rg, 256, 0, stream>>>(wq,  WTqkv,                      768, 768, 768);
    repack_k<1><<<rg, 256, 0, stream>>>(wk,  WTqkv + (size_t)768*768,    768, 768, 768);
    repack_k<1><<<rg, 256, 0, stream>>>(wvw, WTqkv + (size_t)2*768*768,  768, 768, 768);
    repack_k<0><<<rg, 256, 0, stream>>>(wp,  WTp, 768, 768, 768);
    repack_k<0><<<dim3(48, 12), 256, 0, stream>>>(w1, WT1, 768, 3072, 768);
    repack_k<0><<<dim3(12, 48), 256, 0, stream>>>(w2, WT2, 3072, 768, 3072);

    // --- attention sublayer ---
    ln_k<<<MM, 256, 0, stream>>>(x, g1, be1, hbf);
    gemm_bf16<1><<<dim3(18, 64), 256, 0, stream>>>(hbf, WTqkv, MM, 2304, CC,
        qb, kb, vb, bq, bk, bv, nullptr, nullptr);
    vtrans_k<<<48 * 32, 256, 0, stream>>>(vb, vtb);
    attn_k<<<48 * 16, 256, 0, stream>>>(qb, kb, vtb, attnb);
    gemm_bf16<2><<<dim3(6, 64), 256, 0, stream>>>(attnb, WTp, MM, CC, CC,
        out, nullptr, nullptr, bp, nullptr, nullptr, x, nullptr);

    // --- MLP sublayer ---
    ln_k<<<MM, 256, 0, stream>>>(out, g2, be2, hbf);
    gemm_bf16<3><<<dim3(24, 64), 256, 0, stream>>>(hbf, WT1, MM, C4, CC,
        nullptr, nullptr, nullptr, b1, nullptr, nullptr, nullptr, midb);
    gemm_bf16<2><<<dim3(6, 64), 256, 0, stream>>>(midb, WT2, MM, CC, C4,
        out, nullptr, nullptr, b2, nullptr, nullptr, out, nullptr);
}

// Round 5
// 313.611 us; speedup vs baseline: 15.0328x; 1.0917x over previous
//
#include <hip/hip_runtime.h>
#include <hip/hip_bf16.h>
#include <math.h>

#define BB 4
#define TT 2048
#define CC 768
#define HH 12
#define HDIM 64
#define C4 3072
#define MM (BB*TT)   // 8192 rows
#define EPSL 1e-5f

typedef __bf16 bf16x8 __attribute__((ext_vector_type(8)));
typedef float f32x4 __attribute__((ext_vector_type(4)));

__device__ __forceinline__ ushort f2bf(float f) {
    union { float f; unsigned u; } v; v.f = f;
    unsigned r = v.u + 0x7fffu + ((v.u >> 16) & 1u);
    return (ushort)(r >> 16);
}

__device__ __forceinline__ void glds16(const void* g, void* l) {
    __builtin_amdgcn_global_load_lds(
        (const __attribute__((address_space(1))) void*)g,
        (__attribute__((address_space(3))) void*)l, 16, 0, 0);
}

// ---------------------------------------------------------------------------
// LayerNorm: one block per row, fp32 in -> bf16 out
// ---------------------------------------------------------------------------
__global__ __launch_bounds__(256) void ln_k(const float* __restrict__ X,
                                            const float* __restrict__ G,
                                            const float* __restrict__ Be,
                                            ushort* __restrict__ O)
{
    int row = blockIdx.x;
    const float* xr = X + (size_t)row * CC;
    int t = threadIdx.x;
    float v0 = xr[t], v1 = xr[t + 256], v2 = xr[t + 512];
    float s  = v0 + v1 + v2;
    float sq = v0*v0 + v1*v1 + v2*v2;
    #pragma unroll
    for (int off = 32; off; off >>= 1) {
        s  += __shfl_xor(s,  off);
        sq += __shfl_xor(sq, off);
    }
    __shared__ float red[8];
    int wv = t >> 6, ln = t & 63;
    if (ln == 0) { red[wv] = s; red[4 + wv] = sq; }
    __syncthreads();
    s  = red[0] + red[1] + red[2] + red[3];
    sq = red[4] + red[5] + red[6] + red[7];
    float mu  = s * (1.0f / CC);
    float var = sq * (1.0f / CC) - mu * mu;
    float rs  = rsqrtf(var + EPSL);
    ushort* orow = O + (size_t)row * CC;
    orow[t]       = f2bf((v0 - mu) * rs * G[t]       + Be[t]);
    orow[t + 256] = f2bf((v1 - mu) * rs * G[t + 256] + Be[t + 256]);
    orow[t + 512] = f2bf((v2 - mu) * rs * G[t + 512] + Be[t + 512]);
}

// ---------------------------------------------------------------------------
// Weight repack: fp32 W -> bf16 W^T [N][K] via 64x64 LDS transpose tile.
// MODE 0: W row-major [K,N].  MODE 1: W per-head [H][768][64] (wq/wk/wv).
// ---------------------------------------------------------------------------
template<int MODE>
__global__ __launch_bounds__(256) void repack_k(const float* __restrict__ W,
                                                ushort* __restrict__ WT,
                                                int K, int N, int outStride)
{
    __shared__ float tl[64][65];
    int n0 = blockIdx.x * 64, k0 = blockIdx.y * 64;
    int c = threadIdx.x & 63, rr = threadIdx.x >> 6;
    #pragma unroll
    for (int i = 0; i < 16; ++i) {
        int r = i * 4 + rr;
        float v;
        if (MODE == 0) v = W[(size_t)(k0 + r) * N + n0 + c];
        else           v = W[((size_t)(n0 >> 6) * CC + k0 + r) * 64 + c];
        tl[r][c] = v;
    }
    __syncthreads();
    #pragma unroll
    for (int i = 0; i < 16; ++i) {
        int r = i * 4 + rr;   // n within tile
        WT[(size_t)(n0 + r) * outStride + k0 + c] = f2bf(tl[c][r]);
    }
}

// ---------------------------------------------------------------------------
// bf16 MFMA GEMM (m97 structure): C[M,N] = A[M,K] @ BT[N,K]^T, fp32 accum.
// XCD-chunked blockIdx swizzle (T1): each XCD owns contiguous output rows ->
// A-panel reuse in its private L2.
// EPI 1: QKV -> bf16 q/k/v in [B][H][T][64] (+per-segment bias)
// EPI 2: f32 out = acc + bias + resid
// EPI 3: bf16 out = relu(acc + bias)
// ---------------------------------------------------------------------------
template<int EPI>
__global__ __launch_bounds__(256) void gemm_bf16(
    const ushort* __restrict__ A, const ushort* __restrict__ BT,
    int M, int N, int K,
    void* __restrict__ ov0, void* __restrict__ ov1, void* __restrict__ ov2,
    const float* __restrict__ bias0, const float* __restrict__ bias1,
    const float* __restrict__ bias2,
    const float* __restrict__ resid, ushort* __restrict__ obf)
{
    __shared__ ushort Al[128 * 32];
    __shared__ ushort Bl[128 * 32];
    int nbx = gridDim.x;
    int nwg = nbx * gridDim.y;
    int orig = blockIdx.y * nbx + blockIdx.x;
    int swz = orig;
    if ((nwg & 7) == 0) { int cpx = nwg >> 3; swz = (orig & 7) * cpx + (orig >> 3); }
    int bn = swz % nbx, bm = swz / nbx;

    int tid = threadIdx.x;
    int lane = tid & 63;
    int w = tid >> 6;
    int wr = (w >> 1) * 64, wc = (w & 1) * 64;
    int fr = lane & 15, kh = lane >> 4;

    f32x4 acc[4][4] = {};

    const size_t aRow = (size_t)bm * 128;
    const size_t bRow = (size_t)bn * 128;

    for (int k0 = 0; k0 < K; k0 += 32) {
        #pragma unroll
        for (int r = 0; r < 2; ++r) {
            int e = r * 256 + tid;
            glds16(A  + (aRow + (e >> 2)) * K + k0 + (e & 3) * 8, Al + e * 8);
            glds16(BT + (bRow + (e >> 2)) * K + k0 + (e & 3) * 8, Bl + e * 8);
        }
        __syncthreads();
        bf16x8 av[4], bv[4];
        #pragma unroll
        for (int i = 0; i < 4; ++i)
            av[i] = *(const bf16x8*)&Al[(wr + i * 16 + fr) * 32 + kh * 8];
        #pragma unroll
        for (int i = 0; i < 4; ++i)
            bv[i] = *(const bf16x8*)&Bl[(wc + i * 16 + fr) * 32 + kh * 8];
        #pragma unroll
        for (int i = 0; i < 4; ++i)
            #pragma unroll
            for (int j = 0; j < 4; ++j)
                acc[i][j] = __builtin_amdgcn_mfma_f32_16x16x32_bf16(av[i], bv[j], acc[i][j], 0, 0, 0);
        __syncthreads();
    }

    // C/D layout (m89-verified): col = lane&15, row = (lane>>4)*4 + r
    if (EPI == 1) {
        int seg = (bn * 128) / CC;
        ushort* op = (ushort*)(seg == 0 ? ov0 : (seg == 1 ? ov1 : ov2));
        const float* bsp = seg == 0 ? bias0 : (seg == 1 ? bias1 : bias2);
        int cb = bn * 128 - seg * CC + wc;   // multiple of 64
        int h = cb >> 6;
        #pragma unroll
        for (int i = 0; i < 4; ++i) {
            int row0 = bm * 128 + wr + i * 16 + kh * 4;
            int b = row0 >> 11;
            int t0 = row0 & (TT - 1);
            #pragma unroll
            for (int j = 0; j < 4; ++j) {
                int col = cb + j * 16 + fr;
                int d = col & 63;
                float bsv = bsp[col];
                #pragma unroll
                for (int r = 0; r < 4; ++r)
                    op[((size_t)(b * HH + h) * TT + t0 + r) * 64 + d] =
                        f2bf(acc[i][j][r] + bsv);
            }
        }
    } else if (EPI == 2) {
        float* o0 = (float*)ov0;
        int cb = bn * 128 + wc;
        #pragma unroll
        for (int i = 0; i < 4; ++i) {
            int row0 = bm * 128 + wr + i * 16 + kh * 4;
            #pragma unroll
            for (int j = 0; j < 4; ++j) {
                int col = cb + j * 16 + fr;
                float bsv = bias0[col];
                #pragma unroll
                for (int r = 0; r < 4; ++r) {
                    size_t idx = (size_t)(row0 + r) * N + col;
                    o0[idx] = acc[i][j][r] + bsv + resid[idx];
                }
            }
        }
    } else {  // EPI 3
        int cb = bn * 128 + wc;
        #pragma unroll
        for (int i = 0; i < 4; ++i) {
            int row0 = bm * 128 + wr + i * 16 + kh * 4;
            #pragma unroll
            for (int j = 0; j < 4; ++j) {
                int col = cb + j * 16 + fr;
                float bsv = bias0[col];
                #pragma unroll
                for (int r = 0; r < 4; ++r) {
                    float v = fmaxf(acc[i][j][r] + bsv, 0.f);
                    obf[(size_t)(row0 + r) * N + col] = f2bf(v);
                }
            }
        }
    }
}

// ---------------------------------------------------------------------------
// V transpose: bf16 [B,H,T,64] -> [B,H,64,T] (per (b,h), 64x64 LDS tiles)
// ---------------------------------------------------------------------------
__global__ __launch_bounds__(256) void vtrans_k(const ushort* __restrict__ V,
                                                ushort* __restrict__ Vt)
{
    __shared__ ushort tl[64][72];
    int blk = blockIdx.x;
    int tt = blk & 31, bh = blk >> 5;
    size_t base = (size_t)bh * TT * 64;
    int t0 = tt * 64;
    int e = threadIdx.x;
    int rr = e >> 3, cc8 = (e & 7) * 8;
    #pragma unroll
    for (int p = 0; p < 2; ++p) {
        int t = p * 32 + rr;
        *(uint4*)&tl[t][cc8] = *(const uint4*)&V[base + (size_t)(t0 + t) * 64 + cc8];
    }
    __syncthreads();
    #pragma unroll
    for (int p = 0; p < 2; ++p) {
        int d = p * 32 + rr;
        ushort tmp[8];
        #pragma unroll
        for (int i = 0; i < 8; ++i) tmp[i] = tl[cc8 + i][d];
        *(uint4*)&Vt[base + (size_t)d * TT + t0 + cc8] = *(uint4*)tmp;
    }
}

// ---------------------------------------------------------------------------
// Flash attention, bf16 MFMA, work-balanced (pair i,31-i => 33 tiles/block).
// Skip-max fast path: per tile only a per-lane max + __all bound check; the
// exact cross-lane row max + rescale runs only when max grows > 11.5 (log2).
// Exact softmax either way. Q pre-scaled by log2(e). Deferred sum reduce.
// XCD swizzle groups pairs of the same (b,h) for K/V L2 reuse.
// ---------------------------------------------------------------------------
__global__ __launch_bounds__(256) void attn_k(const ushort* __restrict__ Q,
                                              const ushort* __restrict__ Kb,
                                              const ushort* __restrict__ Vt,
                                              ushort* __restrict__ Ob)
{
    __shared__ ushort Kl[64][72];
    __shared__ ushort Vl[64][72];
    __shared__ ushort Pl[4][16][72];

    int orig = blockIdx.x;                 // nwg = 768
    int swz = (orig & 7) * 96 + (orig >> 3);
    int pair = swz & 15;
    int bh = swz >> 4;
    int b = bh / HH, h = bh - b * HH;
    int tid = threadIdx.x, lane = tid & 63, w = tid >> 6;
    int c = lane & 15, g = lane >> 4;
    size_t base = (size_t)bh * TT * 64;
    int srow = tid >> 3, scol = (tid & 7) * 8;
    const float LOG2E = 1.44269504088896340736f;

    #pragma unroll
    for (int sel = 0; sel < 2; ++sel) {
        int qt = sel ? (31 - pair) : pair;
        int q0 = qt * 64;

        // wave's Q A-fragments (16 rows x 64 d), scaled by log2e, in regs
        bf16x8 aq[2];
        #pragma unroll
        for (int kc = 0; kc < 2; ++kc) {
            bf16x8 raw = *(const bf16x8*)&Q[base + (size_t)(q0 + w * 16 + c) * 64 + kc * 32 + g * 8];
            #pragma unroll
            for (int e = 0; e < 8; ++e)
                raw[e] = (__bf16)((float)raw[e] * LOG2E);
            aq[kc] = raw;
        }

        f32x4 oa[4] = {};
        float mrun[4] = {-INFINITY, -INFINITY, -INFINITY, -INFINITY};
        float lrun[4] = {0.f, 0.f, 0.f, 0.f};

        for (int kv0 = 0; kv0 <= q0; kv0 += 64) {
            __syncthreads();
            #pragma unroll
            for (int p = 0; p < 2; ++p) {
                int r = p * 32 + srow;
                *(uint4*)&Kl[r][scol] = *(const uint4*)&Kb[base + (size_t)(kv0 + r) * 64 + scol];
                *(uint4*)&Vl[r][scol] = *(const uint4*)&Vt[base + (size_t)r * TT + kv0 + scol];
            }
            __syncthreads();

            // S[16 q][64 kv] = Qs @ K^T  (log2-domain scores)
            f32x4 sa[4] = {};
            #pragma unroll
            for (int kc = 0; kc < 2; ++kc)
                #pragma unroll
                for (int j = 0; j < 4; ++j) {
                    bf16x8 kf = *(const bf16x8*)&Kl[j * 16 + c][kc * 32 + g * 8];
                    sa[j] = __builtin_amdgcn_mfma_f32_16x16x32_bf16(aq[kc], kf, sa[j], 0, 0, 0);
                }

            if (kv0 == q0) {   // diagonal tile: causal mask
                #pragma unroll
                for (int j = 0; j < 4; ++j)
                    #pragma unroll
                    for (int r = 0; r < 4; ++r)
                        if (j * 16 + c > w * 16 + g * 4 + r) sa[j][r] = -1e30f;
            }

            // skip-max fast path: per-lane max only, no cross-lane reduce
            float vlmax = sa[0][0];
            #pragma unroll
            for (int j = 0; j < 4; ++j)
                #pragma unroll
                for (int r = 0; r < 4; ++r) vlmax = fmaxf(vlmax, sa[j][r]);
            float mmin = fminf(fminf(mrun[0], mrun[1]), fminf(mrun[2], mrun[3]));
            if (!__all(vlmax <= mmin + 11.5f)) {
                // exact path: cross-lane row max + rescale
                #pragma unroll
                for (int r = 0; r < 4; ++r) {
                    float m0 = fmaxf(fmaxf(sa[0][r], sa[1][r]), fmaxf(sa[2][r], sa[3][r]));
                    #pragma unroll
                    for (int off = 8; off; off >>= 1) m0 = fmaxf(m0, __shfl_xor(m0, off));
                    float mnew = fmaxf(mrun[r], m0);
                    float sc = __builtin_amdgcn_exp2f(mrun[r] - mnew);
                    lrun[r] *= sc;
                    #pragma unroll
                    for (int j = 0; j < 4; ++j) oa[j][r] *= sc;
                    mrun[r] = mnew;
                }
            }
            // exps + per-lane partial sums (no cross-lane reduce here)
            #pragma unroll
            for (int r = 0; r < 4; ++r) {
                float ps = 0.f;
                #pragma unroll
                for (int j = 0; j < 4; ++j) {
                    float p = __builtin_amdgcn_exp2f(sa[j][r] - mrun[r]);
                    sa[j][r] = p;
                    ps += p;
                }
                lrun[r] += ps;
            }

            // P -> bf16 -> per-wave LDS (C/D layout -> A-frag layout)
            #pragma unroll
            for (int r = 0; r < 4; ++r)
                #pragma unroll
                for (int j = 0; j < 4; ++j)
                    Pl[w][g * 4 + r][j * 16 + c] = (ushort)__builtin_bit_cast(unsigned short, (__bf16)sa[j][r]);

            bf16x8 pf[2];
            #pragma unroll
            for (int kc = 0; kc < 2; ++kc)
                pf[kc] = *(const bf16x8*)&Pl[w][c][kc * 32 + g * 8];

            // O[16 q][64 d] += P @ V
            #pragma unroll
            for (int kc = 0; kc < 2; ++kc)
                #pragma unroll
                for (int j = 0; j < 4; ++j) {
                    bf16x8 vf = *(const bf16x8*)&Vl[j * 16 + c][kc * 32 + g * 8];
                    oa[j] = __builtin_amdgcn_mfma_f32_16x16x32_bf16(pf[kc], vf, oa[j], 0, 0, 0);
                }
        }

        // final row-sum of deferred partials, then normalize + store
        float inv[4];
        #pragma unroll
        for (int r = 0; r < 4; ++r) {
            float l = lrun[r];
            #pragma unroll
            for (int off = 8; off; off >>= 1) l += __shfl_xor(l, off);
            inv[r] = 1.0f / l;
        }
        size_t orow = (size_t)b * TT + q0 + w * 16;
        #pragma unroll
        for (int j = 0; j < 4; ++j)
            #pragma unroll
            for (int r = 0; r < 4; ++r) {
                float v = oa[j][r] * inv[r];
                Ob[(orow + g * 4 + r) * CC + h * 64 + j * 16 + c] = f2bf(v);
            }
    }
}

// ---------------------------------------------------------------------------
// Orchestration. ws layout (ushorts), S = MM*CC = 6291456:
//   WTqkv [2304*768]  WTp [768*768]  WT1 [3072*768]  WT2 [768*3072]
//   hbf [S]  attnb [S]  qb [S]  kb [S]  vb [S]  vtb [S]
//   midb [MM*3072] aliases qb..vtb exactly (dead after attention)
// Total ~89.7 MB.
// ---------------------------------------------------------------------------
extern "C" void kernel_launch(void* const* d_in, const int* in_sizes, int n_in,
                              void* d_out, int out_size, void* d_ws, size_t ws_size,
                              hipStream_t stream)
{
    const float* x   = (const float*)d_in[0];
    const float* wq  = (const float*)d_in[1];
    const float* bq  = (const float*)d_in[2];
    const float* wk  = (const float*)d_in[3];
    const float* bk  = (const float*)d_in[4];
    const float* wvw = (const float*)d_in[5];
    const float* bv  = (const float*)d_in[6];
    const float* wp  = (const float*)d_in[7];
    const float* bp  = (const float*)d_in[8];
    const float* w1  = (const float*)d_in[9];
    const float* b1  = (const float*)d_in[10];
    const float* w2  = (const float*)d_in[11];
    const float* b2  = (const float*)d_in[12];
    const float* g1  = (const float*)d_in[13];
    const float* be1 = (const float*)d_in[14];
    const float* g2  = (const float*)d_in[15];
    const float* be2 = (const float*)d_in[16];

    float* out = (float*)d_out;
    const size_t S = (size_t)MM * CC;

    ushort* wsu   = (ushort*)d_ws;
    ushort* WTqkv = wsu;
    ushort* WTp   = WTqkv + (size_t)2304 * 768;
    ushort* WT1   = WTp   + (size_t)768 * 768;
    ushort* WT2   = WT1   + (size_t)3072 * 768;
    ushort* hbf   = WT2   + (size_t)768 * 3072;
    ushort* attnb = hbf   + S;
    ushort* qb    = attnb + S;
    ushort* kb    = qb + S;
    ushort* vb    = kb + S;
    ushort* vtb   = vb + S;
    ushort* midb  = qb;   // [8192][3072] bf16 == qb..vtb exactly

    dim3 rg(12, 12);
    repack_k<1><<<rg, 256, 0, stream>>>(wq,  WTqkv,                      768, 768, 768);
    repack_k<1><<<rg, 256, 0, stream>>>(wk,  WTqkv + (size_t)768*768,    768, 768, 768);
    repack_k<1><<<rg, 256, 0, stream>>>(wvw, WTqkv + (size_t)2*768*768,  768, 768, 768);
    repack_k<0><<<rg, 256, 0, stream>>>(wp,  WTp, 768, 768, 768);
    repack_k<0><<<dim3(48, 12), 256, 0, stream>>>(w1, WT1, 768, 3072, 768);
    repack_k<0><<<dim3(12, 48), 256, 0, stream>>>(w2, WT2, 3072, 768, 3072);

    // --- attention sublayer ---
    ln_k<<<MM, 256, 0, stream>>>(x, g1, be1, hbf);
    gemm_bf16<1><<<dim3(18, 64), 256, 0, stream>>>(hbf, WTqkv, MM, 2304, CC,
        qb, kb, vb, bq, bk, bv, nullptr, nullptr);
    vtrans_k<<<48 * 32, 256, 0, stream>>>(vb, vtb);
    attn_k<<<48 * 16, 256, 0, stream>>>(qb, kb, vtb, attnb);
    gemm_bf16<2><<<dim3(6, 64), 256, 0, stream>>>(attnb, WTp, MM, CC, CC,
        out, nullptr, nullptr, bp, nullptr, nullptr, x, nullptr);

    // --- MLP sublayer ---
    ln_k<<<MM, 256, 0, stream>>>(out, g2, be2, hbf);
    gemm_bf16<3><<<dim3(24, 64), 256, 0, stream>>>(hbf, WT1, MM, C4, CC,
        nullptr, nullptr, nullptr, b1, nullptr, nullptr, nullptr, midb);
    gemm_bf16<2><<<dim3(6, 64), 256, 0, stream>>>(midb, WT2, MM, CC, C4,
        out, nullptr, nullptr, b2, nullptr, nullptr, out, nullptr);
}